// Round 6
// baseline (144.209 us; speedup 1.0000x reference)
//
#include <hip/hip_runtime.h>
#include <stdint.h>

#define BB 8
#define NN 50000
#define SCORE_THR 0.99f
#define NMS_THR 0.5f
#define MAX_DET 100
#define K_PRE 1024
#define CAP 2048
#define KEEP_CAP 128
#define CNT_STRIDE 64      // ints => 256 B per counter
#define T_MAX 16           // K_PRE / 64
#define NPAIR 136          // T_MAX*(T_MAX+1)/2
#define TRI_WORDS 8704     // 64 * NPAIR  (u64 words per (b,c))

typedef unsigned long long u64;
typedef unsigned int u32;
typedef __attribute__((ext_vector_type(2))) unsigned long long u64x2;

// ws layout (bytes):
//   int    cand_cnt[64*CNT_STRIDE]  @ 0          (16 KB padded counters)
//   u64    cand_keys[64*CAP]        @ 16896      (1 MB)
//   u64    sk_g[64*K_PRE]           @ 1065472    (512 KB)  sorted keys
//   float4 box4[64*K_PRE]           @ 1589760    (1 MB)    sorted boxes
//   u64    rowmask[64*TRI_WORDS]    @ 2638336    (~4.25 MB) triangular bit-matrix

__global__ void k_init(int* __restrict__ cnts) {
    for (int i = threadIdx.x; i < 64 * CNT_STRIDE; i += 256) cnts[i] = 0;
}

__global__ __launch_bounds__(256) void k_filter(const float* __restrict__ cls,
                                                int* __restrict__ cand_cnt,
                                                u64* __restrict__ cand_keys) {
    __shared__ int wcnt[8][4];
    __shared__ int woff[8][4];
    __shared__ int cbase[8];
    int b = blockIdx.y;
    int tid = threadIdx.x;
    int lane = tid & 63, w = tid >> 6;
    int n = blockIdx.x * 256 + tid;
    bool vn = n < NN;
    float s[8];
    if (vn) {
        const float4* p = (const float4*)(cls + ((size_t)b * NN + n) * 8);
        float4 a = p[0], b2 = p[1];
        s[0] = a.x; s[1] = a.y; s[2] = a.z; s[3] = a.w;
        s[4] = b2.x; s[5] = b2.y; s[6] = b2.z; s[7] = b2.w;
    } else {
        #pragma unroll
        for (int c = 0; c < 8; ++c) s[c] = 0.f;
    }
    u64 bal[8];
    #pragma unroll
    for (int c = 0; c < 8; ++c) {
        bool pred = vn && (s[c] > SCORE_THR);
        bal[c] = __ballot(pred);
        if (lane == 0) wcnt[c][w] = (int)__popcll(bal[c]);
    }
    __syncthreads();
    if (tid < 8) {
        int c = tid, acc = 0;
        #pragma unroll
        for (int ww = 0; ww < 4; ++ww) { woff[c][ww] = acc; acc += wcnt[c][ww]; }
        cbase[c] = acc ? atomicAdd(&cand_cnt[(b * 8 + c) * CNT_STRIDE], acc) : 0;
    }
    __syncthreads();
    #pragma unroll
    for (int c = 0; c < 8; ++c) {
        if (vn && (s[c] > SCORE_THR)) {
            int slot = cbase[c] + woff[c][w] + (int)__popcll(bal[c] & ((1ull << lane) - 1ull));
            if (slot < CAP)
                cand_keys[(size_t)(b * 8 + c) * CAP + slot] =
                    ((u64)__float_as_uint(s[c]) << 32) | (u32)(~(u32)n);
        }
    }
}

// distributed rank-sort: block (q, bc) ranks candidates [q*64, q*64+64) of (b,c)
// against all cnt candidates (keys globally distinct => exact permutation)
__global__ __launch_bounds__(64) void k_sort(const float* __restrict__ boxes,
                                             const int* __restrict__ cand_cnt,
                                             const u64* __restrict__ cand_keys,
                                             u64* __restrict__ sk_g,
                                             float4* __restrict__ box4) {
    __shared__ __align__(16) u64 sk_in[CAP];
    int lane = threadIdx.x;
    int q = blockIdx.x;
    int bc = blockIdx.y;
    int b = bc >> 3;
    int cnt = cand_cnt[bc * CNT_STRIDE];
    if (cnt > CAP) cnt = CAP;
    if (q * 64 >= cnt) return;
    int cnt2 = (cnt + 1) & ~1;
    for (int i = lane; i < cnt2; i += 64)
        sk_in[i] = (i < cnt) ? cand_keys[(size_t)bc * CAP + i] : 0ull;
    __syncthreads();
    int i0 = q * 64 + lane;
    u64 k0 = (i0 < cnt) ? sk_in[i0] : 0ull;
    int r0 = 0;
    int nv = cnt2 >> 1;
    const u64x2* skv = (const u64x2*)sk_in;
    #pragma unroll 4
    for (int jv = 0; jv < nv; ++jv) {
        u64x2 kk = skv[jv];
        r0 += (kk.x > k0); r0 += (kk.y > k0);
    }
    if (i0 < cnt && r0 < K_PRE) {
        sk_g[(size_t)bc * K_PRE + r0] = k0;
        u32 n = ~(u32)k0;
        box4[(size_t)bc * K_PRE + r0] =
            *(const float4*)(boxes + ((size_t)b * NN + n) * 4);
    }
}

// triangular IoU bit matrix: block (pair p, bc); word (row i, tile tj) over cols j<=i
__global__ __launch_bounds__(256) void k_iou(const int* __restrict__ cand_cnt,
                                             const float4* __restrict__ box4,
                                             u64* __restrict__ rowmask) {
    int bc = blockIdx.y;
    int p = blockIdx.x;
    int cnt = cand_cnt[bc * CNT_STRIDE];
    int n_cand = cnt < K_PRE ? cnt : K_PRE;
    int ntiles = (n_cand + 63) >> 6;
    int ti = 0, acc = 0;
    while (acc + ti + 1 <= p) { acc += ti + 1; ++ti; }
    int tj = p - acc;
    if (ti >= ntiles) return;
    const float4* bx = box4 + (size_t)bc * K_PRE;
    __shared__ float4 srb[64];
    int tid = threadIdx.x;
    int lane = tid & 63, w = tid >> 6;
    if (tid < 64) srb[tid] = bx[ti * 64 + tid];
    __syncthreads();
    int cg = tj * 64 + lane;
    float4 cb = bx[cg];
    float ca = (cb.z - cb.x) * (cb.w - cb.y);
    u64* out = rowmask + (size_t)bc * TRI_WORDS + 64 * (ti * (ti + 1) / 2) + tj;
    #pragma unroll
    for (int r16 = 0; r16 < 16; ++r16) {
        int r = (w << 4) | r16;
        float4 rb = srb[r];
        float ra = (rb.z - rb.x) * (rb.w - rb.y);
        float iw = fminf(rb.z, cb.z) - fmaxf(rb.x, cb.x);
        float ih = fminf(rb.w, cb.w) - fmaxf(rb.y, cb.y);
        iw = fmaxf(iw, 0.f); ih = fmaxf(ih, 0.f);
        float inter = iw * ih;
        float iou = inter / (ra + ca - inter);
        int rg = ti * 64 + r;
        bool pr = (rg < n_cand) && (cg < n_cand) && ((ti != tj) || (lane < r)) &&
                  (iou > NMS_THR);
        u64 m = __ballot(pr);
        if (lane == 0) out[(size_t)r * (ti + 1)] = m;
    }
}

// fused greedy + final: one block per batch; waves 0-7 run per-class greedy over
// the precomputed bit matrix into LDS, then all threads do the top-100 selection.
__global__ __launch_bounds__(1024) void k_fuse(const float* __restrict__ boxes,
                                               const float* __restrict__ rot,
                                               const float* __restrict__ trans,
                                               const int* __restrict__ cand_cnt,
                                               const u64* __restrict__ sk_g,
                                               const u64* __restrict__ rowmask,
                                               float* __restrict__ out) {
    __shared__ u64 fk[1024];      // 8 strictly-descending runs of 128 (0-padded)
    __shared__ int scnt[8];
    int tid = threadIdx.x;
    int lane = tid & 63, w = tid >> 6;
    int b = blockIdx.x;
    fk[tid] = 0ull;
    __syncthreads();
    if (w < 8) {
        int c = w;
        int bc = b * 8 + c;
        int cnt = cand_cnt[bc * CNT_STRIDE];
        int n_cand = cnt < K_PRE ? cnt : K_PRE;
        int ntiles = (n_cand + 63) >> 6;
        const u64* tri = rowmask + (size_t)bc * TRI_WORDS;
        u64 kept_w[T_MAX];
        #pragma unroll
        for (int t = 0; t < T_MAX; ++t) kept_w[t] = 0ull;
        for (int t = 0; t < ntiles; ++t) {
            int g = t * 64 + lane;
            const u64* base = tri + 64 * (t * (t + 1) / 2) + (size_t)lane * (t + 1);
            u64 supbits = 0;
            #pragma unroll
            for (int ww = 0; ww < T_MAX - 1; ++ww)
                if (ww < t) supbits |= base[ww] & kept_w[ww];
            u64 rowm = base[t];
            bool el = (g < n_cand) && (supbits == 0ull);
            u64 alive = __ballot(el);
            u64 kb = 0;
            while (alive) {
                int j = __ffsll(alive) - 1;
                kb |= (1ull << j);
                u64 colj = __ballot(((rowm >> j) & 1ull) != 0);
                alive &= ~(colj | (1ull << j));
            }
            #pragma unroll
            for (int ww = 0; ww < T_MAX; ++ww)
                if (ww == t) kept_w[ww] = kb;
        }
        // compaction: rank kept candidates in sorted order, emit encoded keys to LDS
        u64 lmask = (1ull << lane) - 1ull;
        int pre = 0;
        #pragma unroll
        for (int t = 0; t < T_MAX; ++t) {
            if (t < ntiles) {
                u64 kb = kept_w[t];
                if ((kb >> lane) & 1ull) {
                    int rank = pre + (int)__popcll(kb & lmask);
                    if (rank < KEEP_CAP) {
                        int i = t * 64 + lane;
                        u64 key = sk_g[(size_t)bc * K_PRE + i];
                        u32 sb = (u32)(key >> 32);
                        u32 n = (~(u32)key) & 0x1FFFFu;
                        int pos = c * K_PRE + i;
                        fk[c * KEEP_CAP + rank] =
                            ((u64)sb << 30) | ((u64)(8191 - pos) << 17) | (u64)n;
                    }
                }
                pre += (int)__popcll(kb);
            }
        }
        if (lane == 0) scnt[c] = pre < KEEP_CAP ? pre : KEEP_CAP;
    }
    __syncthreads();
    int c = tid >> 7, i = tid & 127;
    int cc = scnt[c];
    u64 key = fk[tid];
    int total = 0;
    #pragma unroll
    for (int r = 0; r < 8; ++r) total += scnt[r];
    if (i < cc) {
        // global rank = own index + countGreater in the 7 other runs (binary search)
        int rank = i;
        #pragma unroll
        for (int r = 0; r < 8; ++r) {
            if (r == c) continue;
            int basei = r << 7;
            int lo;
            if (fk[basei + 127] > key) lo = 128;
            else {
                lo = 0;
                #pragma unroll
                for (int s = 64; s > 0; s >>= 1)
                    if (fk[basei + lo + s - 1] > key) lo += s;
            }
            rank += lo;
        }
        if (rank < MAX_DET) {
            u32 n = (u32)(key & 0x1FFFFu);
            int pos = 8191 - (int)((key >> 17) & 0x1FFFu);
            int cls = pos >> 10;
            float osc = __uint_as_float((u32)(key >> 30));
            const float* bp = boxes + ((size_t)b * NN + n) * 4;
            const float* rp = rot + ((size_t)b * NN + n) * 3;
            const float* tp = trans + ((size_t)b * NN + n) * 3;
            int base = b * MAX_DET + rank;
            out[base * 4 + 0] = bp[0];
            out[base * 4 + 1] = bp[1];
            out[base * 4 + 2] = bp[2];
            out[base * 4 + 3] = bp[3];
            out[BB * MAX_DET * 4 + base] = osc;
            out[BB * MAX_DET * 5 + base] = (float)cls;
            float* ro = out + BB * MAX_DET * 6;
            ro[base * 3 + 0] = rp[0];
            ro[base * 3 + 1] = rp[1];
            ro[base * 3 + 2] = rp[2];
            float* to = out + BB * MAX_DET * 6 + BB * MAX_DET * 3;
            to[base * 3 + 0] = tp[0];
            to[base * 3 + 1] = tp[1];
            to[base * 3 + 2] = tp[2];
        }
    }
    if (tid < MAX_DET && tid >= total) {    // rows [total, 100) get the -1 fill
        int base = b * MAX_DET + tid;
        out[base * 4 + 0] = -1.f;
        out[base * 4 + 1] = -1.f;
        out[base * 4 + 2] = -1.f;
        out[base * 4 + 3] = -1.f;
        out[BB * MAX_DET * 4 + base] = -1.f;
        out[BB * MAX_DET * 5 + base] = -1.f;
        float* ro = out + BB * MAX_DET * 6;
        ro[base * 3 + 0] = -1.f;
        ro[base * 3 + 1] = -1.f;
        ro[base * 3 + 2] = -1.f;
        float* to = out + BB * MAX_DET * 6 + BB * MAX_DET * 3;
        to[base * 3 + 0] = -1.f;
        to[base * 3 + 1] = -1.f;
        to[base * 3 + 2] = -1.f;
    }
}

extern "C" void kernel_launch(void* const* d_in, const int* in_sizes, int n_in,
                              void* d_out, int out_size, void* d_ws, size_t ws_size,
                              hipStream_t stream) {
    const float* boxes = (const float*)d_in[0];
    const float* cls   = (const float*)d_in[1];
    const float* rot   = (const float*)d_in[2];
    const float* trans = (const float*)d_in[3];
    char* ws = (char*)d_ws;
    int* cand_cnt  = (int*)ws;
    u64* cand_keys = (u64*)(ws + 16896);
    u64* sk_g      = (u64*)(ws + 1065472);
    float4* box4   = (float4*)(ws + 1589760);
    u64* rowmask   = (u64*)(ws + 2638336);
    float* out = (float*)d_out;

    hipLaunchKernelGGL(k_init, dim3(1), dim3(256), 0, stream, cand_cnt);
    hipLaunchKernelGGL(k_filter, dim3((NN + 255) / 256, BB), dim3(256), 0, stream,
                       cls, cand_cnt, cand_keys);
    hipLaunchKernelGGL(k_sort, dim3(CAP / 64, 64), dim3(64), 0, stream,
                       boxes, cand_cnt, cand_keys, sk_g, box4);
    hipLaunchKernelGGL(k_iou, dim3(NPAIR, 64), dim3(256), 0, stream,
                       cand_cnt, box4, rowmask);
    hipLaunchKernelGGL(k_fuse, dim3(BB), dim3(1024), 0, stream,
                       boxes, rot, trans, cand_cnt, sk_g, rowmask, out);
}